// Round 6
// baseline (24542.032 us; speedup 1.0000x reference)
//
#include <hip/hip_runtime.h>
#include <stdint.h>

// GRU encoder: VOCAB=50257, EMBED=HIDDEN=1024, SEQ=4096.
// Phase 1: x-projections (parallel GEMMs).
// Phase 2: 4096-step scan, 64 persistent WGs x 512 threads, fused (tag|value)
//          cells. ROUND-6 CHANGE (single A/B vs round 5): producers publish
//          with atomic EXCHANGE (RMW) instead of atomic store. An RMW must
//          execute at the coherent point (TCC/MALL), so the value is
//          immediately visible to remote XCDs -- testing the theory that
//          round 1-5's ~3us/exchange was store->visibility lag.

#define HID    1024
#define SEQLEN 4096
#define NWG    64
#define RPW    16      // hidden rows per WG
#define BLOCK  512     // 8 waves; wave w owns rows 16g+2w, 16g+2w+1

typedef unsigned long long u64;

// ---------------------------------------------------------------------------
// Phase 1: C[t,i] = sum_e emb[seq[t],e] * W[i,e]   (block 256, 64x64 tile)
// ---------------------------------------------------------------------------
__global__ __launch_bounds__(256) void proj_gemm(
    const int* __restrict__ seq, const float* __restrict__ emb,
    const float* __restrict__ Wrx, const float* __restrict__ Wzx,
    const float* __restrict__ Wx,
    float* __restrict__ xr, float* __restrict__ xz, float* __restrict__ xh)
{
  __shared__ float As[32][68];
  __shared__ float Bs[32][68];
  __shared__ int   idx[64];

  const float* W = (blockIdx.z == 0) ? Wrx : (blockIdx.z == 1) ? Wzx : Wx;
  float*       C = (blockIdx.z == 0) ? xr  : (blockIdx.z == 1) ? xz  : xh;

  const int tid = threadIdx.x;
  const int t0 = blockIdx.y * 64;
  const int i0 = blockIdx.x * 64;
  if (tid < 64) idx[tid] = seq[t0 + tid];
  __syncthreads();

  float acc[4][4] = {};
  const int tx = tid & 15, ty = tid >> 4;
  const int c4 = (tid & 7) * 4;
  const int r8 = tid >> 3;

  for (int k0 = 0; k0 < HID; k0 += 32) {
    for (int l = 0; l < 2; ++l) {
      const int rr = r8 + l * 32;
      float4 av = *(const float4*)(emb + (size_t)idx[rr] * HID + k0 + c4);
      As[c4+0][rr]=av.x; As[c4+1][rr]=av.y; As[c4+2][rr]=av.z; As[c4+3][rr]=av.w;
      float4 bv = *(const float4*)(W + (size_t)(i0 + rr) * HID + k0 + c4);
      Bs[c4+0][rr]=bv.x; Bs[c4+1][rr]=bv.y; Bs[c4+2][rr]=bv.z; Bs[c4+3][rr]=bv.w;
    }
    __syncthreads();
    #pragma unroll
    for (int k = 0; k < 32; ++k) {
      float a[4], b[4];
      *(float4*)a = *(const float4*)&As[k][ty * 4];
      *(float4*)b = *(const float4*)&Bs[k][tx * 4];
      #pragma unroll
      for (int i = 0; i < 4; ++i)
        #pragma unroll
        for (int j = 0; j < 4; ++j)
          acc[i][j] = fmaf(a[i], b[j], acc[i][j]);
    }
    __syncthreads();
  }
  #pragma unroll
  for (int i = 0; i < 4; ++i) {
    float4 v = make_float4(acc[i][0], acc[i][1], acc[i][2], acc[i][3]);
    *(float4*)(C + (size_t)(t0 + ty * 4 + i) * HID + i0 + tx * 4) = v;
  }
}

// ---------------------------------------------------------------------------
// Fused-cell primitives. Cell = u64 {low: f32 bits, high: step tag}.
// PUBLISH: atomic exchange (RMW) -- executes AT the coherent point, so the
// write is instantly visible to every XCD's coherent loads (vs a relaxed
// agent store, which can linger in the producer-side hierarchy: rounds 1-5).
// CONSUME: one 16B sc0sc1 load returns {val0,tag0,val1,tag1} in one event.
// ---------------------------------------------------------------------------
__device__ __forceinline__ void publish2(u64* cells, int row, float a, float b,
                                         unsigned tag) {
  u64 ca = ((u64)tag << 32) | (u64)__float_as_uint(a);
  u64 cb = ((u64)tag << 32) | (u64)__float_as_uint(b);
  (void)__hip_atomic_exchange(&cells[row],     ca, __ATOMIC_RELAXED,
                              __HIP_MEMORY_SCOPE_AGENT);
  (void)__hip_atomic_exchange(&cells[row + 1], cb, __ATOMIC_RELAXED,
                              __HIP_MEMORY_SCOPE_AGENT);
}

// Poll ONE 16B cell-pair until both tags == want. Nothing left in flight at
// exit (the asm embeds its own vmcnt(0)). Budget bail-out turns pathological
// stalls into an absmax fail instead of a hang.
__device__ __forceinline__ float2 poll_pair(const u64* cells, int pair,
                                            unsigned want, int* budget) {
  const float* p = (const float*)(cells + 2 * pair);
  float4 v;
  for (;;) {
    asm volatile("global_load_dwordx4 %0, %1, off sc0 sc1\n\ts_waitcnt vmcnt(0)"
                 : "=v"(v) : "v"(p) : "memory");
    if (__float_as_uint(v.y) == want && __float_as_uint(v.w) == want) break;
    if (--(*budget) <= 0) break;
  }
  return make_float2(v.x, v.z);
}

// ---------------------------------------------------------------------------
// Phase 2: persistent scan. WG g owns rows [16g,16g+16); wave w (of 8) owns
// rows 16g+2w, +1; lane l covers h-columns {q*256+4l+j} (q-strided,
// conflict-free LDS reads). Consumer thread tid polls rows {2tid, 2tid+1}.
// Per step: poll h -> B1 -> gates -> publish r*h -> poll rh -> B2 ->
// candidate -> publish h. 2 visibility events, 2 barriers per step.
// ---------------------------------------------------------------------------
__global__ __launch_bounds__(BLOCK, 2) void rnn_scan(
    const float* __restrict__ Wzh, const float* __restrict__ Wrh,
    const float* __restrict__ Whh,
    const float* __restrict__ xz, const float* __restrict__ xr,
    const float* __restrict__ xh,
    u64* __restrict__ hcell,     // [2][HID]
    u64* __restrict__ rhcell,    // [2][HID]
    float* __restrict__ out)
{
  const int tid  = threadIdx.x;
  const int wave = tid >> 6, lane = tid & 63;
  const int g    = blockIdx.x;
  const int rowA = g * RPW + wave * 2;

  __shared__ float h_lds[HID];
  __shared__ float rh_lds[HID];

  // Weights: wgt[m][rr][q*4+j] = Wm[rowA+rr][q*256 + 4*lane + j].
  float wgt[3][2][16];
  #pragma unroll
  for (int m = 0; m < 3; ++m) {
    const float* Wm = (m == 0) ? Wzh : (m == 1) ? Wrh : Whh;
    #pragma unroll
    for (int rr = 0; rr < 2; ++rr) {
      const float* p = Wm + (size_t)(rowA + rr) * HID + lane * 4;
      #pragma unroll
      for (int q = 0; q < 4; ++q) {
        float4 v = *(const float4*)(p + q * 256);
        wgt[m][rr][q*4+0] = v.x; wgt[m][rr][q*4+1] = v.y;
        wgt[m][rr][q*4+2] = v.z; wgt[m][rr][q*4+3] = v.w;
      }
    }
  }

  int budget = 1 << 21;
  float xzv[2], xrv[2], xhv[2], zv[2], hprev[2];

  for (int t = 1; t <= SEQLEN; ++t) {
    // ---- exchange 1: h_{t-1} (tag t-1, parity (t-1)&1) ----
    if (t == 1) {
      *(float2*)&h_lds[2 * tid] = make_float2(0.f, 0.f);
    } else {
      float2 hv = poll_pair(hcell + ((t - 1) & 1) * HID, tid,
                            (unsigned)(t - 1), &budget);
      *(float2*)&h_lds[2 * tid] = hv;
    }

    // x-projection rows for this step: latency hides under B1 + gate matvec.
    if (lane == 0) {
      #pragma unroll
      for (int rr = 0; rr < 2; ++rr) {
        xzv[rr] = xz[(size_t)(t - 1) * HID + rowA + rr];
        xrv[rr] = xr[(size_t)(t - 1) * HID + rowA + rr];
        xhv[rr] = xh[(size_t)(t - 1) * HID + rowA + rr];
      }
    }
    __syncthreads();                                   // [B1]

    // gate dots over q-strided 16 columns, 64-lane shuffle reduce.
    float hr[16];
    #pragma unroll
    for (int q = 0; q < 4; ++q)
      *(float4*)&hr[q*4] = *(const float4*)&h_lds[q * 256 + lane * 4];
    float az[2] = {0.f, 0.f}, ar[2] = {0.f, 0.f};
    #pragma unroll
    for (int rr = 0; rr < 2; ++rr)
      #pragma unroll
      for (int c = 0; c < 16; ++c) {
        az[rr] = fmaf(wgt[0][rr][c], hr[c], az[rr]);
        ar[rr] = fmaf(wgt[1][rr][c], hr[c], ar[rr]);
      }
    #pragma unroll
    for (int m = 1; m < 64; m <<= 1) {
      az[0] += __shfl_xor(az[0], m, 64);
      az[1] += __shfl_xor(az[1], m, 64);
      ar[0] += __shfl_xor(ar[0], m, 64);
      ar[1] += __shfl_xor(ar[1], m, 64);
    }
    if (lane == 0) {
      float rh[2];
      #pragma unroll
      for (int rr = 0; rr < 2; ++rr) {
        hprev[rr] = h_lds[rowA + rr];
        zv[rr]    = 1.f / (1.f + __expf(-(xzv[rr] + az[rr])));
        float rg  = 1.f / (1.f + __expf(-(xrv[rr] + ar[rr])));
        rh[rr]    = rg * hprev[rr];
      }
      publish2(rhcell + (t & 1) * HID, rowA, rh[0], rh[1], (unsigned)t);
    }

    // ---- exchange 2: (r*h)_t (tag t, parity t&1) ----
    {
      float2 rv = poll_pair(rhcell + (t & 1) * HID, tid, (unsigned)t, &budget);
      *(float2*)&rh_lds[2 * tid] = rv;
    }
    __syncthreads();                                   // [B2]

    float rr16[16];
    #pragma unroll
    for (int q = 0; q < 4; ++q)
      *(float4*)&rr16[q*4] = *(const float4*)&rh_lds[q * 256 + lane * 4];
    float ac[2] = {0.f, 0.f};
    #pragma unroll
    for (int rr = 0; rr < 2; ++rr)
      #pragma unroll
      for (int c = 0; c < 16; ++c)
        ac[rr] = fmaf(wgt[2][rr][c], rr16[c], ac[rr]);
    #pragma unroll
    for (int m = 1; m < 64; m <<= 1) {
      ac[0] += __shfl_xor(ac[0], m, 64);
      ac[1] += __shfl_xor(ac[1], m, 64);
    }
    if (lane == 0) {
      float hn[2];
      #pragma unroll
      for (int rr = 0; rr < 2; ++rr) {
        float cand = tanhf(xhv[rr] + ac[rr]);
        hn[rr]     = zv[rr] * hprev[rr] + (1.f - zv[rr]) * cand;
      }
      publish2(hcell + (t & 1) * HID, rowA, hn[0], hn[1], (unsigned)t);
      if (t == SEQLEN) { out[rowA] = hn[0]; out[rowA + 1] = hn[1]; }
    }
  }
}

// ---------------------------------------------------------------------------
extern "C" void kernel_launch(void* const* d_in, const int* in_sizes, int n_in,
                              void* d_out, int out_size, void* d_ws, size_t ws_size,
                              hipStream_t stream) {
  (void)in_sizes; (void)n_in; (void)out_size; (void)ws_size;

  const int*   seq = (const int*)d_in[0];
  const float* emb = (const float*)d_in[1];
  const float* Wrx = (const float*)d_in[2];
  const float* Wrh = (const float*)d_in[3];
  const float* Wzx = (const float*)d_in[4];
  const float* Wzh = (const float*)d_in[5];
  const float* Wx  = (const float*)d_in[6];
  const float* Wh  = (const float*)d_in[7];

  char* ws = (char*)d_ws;
  const size_t PROJ = (size_t)SEQLEN * HID * sizeof(float);   // 16 MB each
  float* xr    = (float*)(ws);
  float* xz    = (float*)(ws + PROJ);
  float* xh    = (float*)(ws + 2 * PROJ);
  u64*   hcell = (u64*)(ws + 3 * PROJ);                       // [2][HID]
  u64*   rhcell= hcell + 2 * HID;                             // [2][HID]

  // Tag reset every launch: 0xFFFFFFFF never matches a wanted tag in [1,4096].
  (void)hipMemsetAsync(hcell, 0xFF, 4 * HID * sizeof(u64), stream);

  proj_gemm<<<dim3(HID / 64, SEQLEN / 64, 3), 256, 0, stream>>>(
      seq, emb, Wrx, Wzx, Wx, xr, xz, xh);

  rnn_scan<<<dim3(NWG), BLOCK, 0, stream>>>(
      Wzh, Wrh, Wh, xz, xr, xh, hcell, rhcell, (float*)d_out);
}